// Round 19
// baseline (261.727 us; speedup 1.0000x reference)
//
#include <hip/hip_runtime.h>
#include <hip/hip_bf16.h>

// Problem constants
#define NB 128     // batch
#define AA 128     // conv1 out channels
#define BB 32      // capsule types
#define CC 10      // classes
#define KK 6       // primary grid
#define DD 16      // pose dim
#define NN 1152    // B*K*K
#define H1 14      // conv1 out spatial
#define CH2 544    // B*D+B
#define NG 4608    // GEMM N = NB*36
#define KG 1152    // GEMM K = 128*9
#define MG 576     // GEMM M padded (544 -> 9*64)
#define NSEG 6     // routing n-segments (768 blocks = 3/CU)

typedef short bfrag8 __attribute__((ext_vector_type(8)));   // 8 bf16 (4 VGPRs)
typedef float facc4 __attribute__((ext_vector_type(4)));    // 4 fp32 acc

__device__ __forceinline__ unsigned short f2bf(float f) {   // RNE f32->bf16
    unsigned u = __float_as_uint(f);
    u += 0x7FFF + ((u >> 16) & 1);
    return (unsigned short)(u >> 16);
}
__device__ __forceinline__ float bf2f(unsigned short s) {
    return __uint_as_float(((unsigned)s) << 16);
}

// ---------------- conv1: block = (16-oc group, b); full image in LDS ----------------
// grid (8, 128) = 1024 blocks, 256 threads, ~20.5 KB LDS -> 4 blocks/CU.
// Thread (oc_l = tid/14, oy = tid%14), tid < 224; row-per-thread inner loop.
// Epilogue: per-channel bn1 partials part1s/part1q[c][b] (deterministic order).
__global__ __launch_bounds__(256) void k_conv1(const float* __restrict__ x,
                                               const float* __restrict__ w,
                                               float* __restrict__ h,
                                               float* __restrict__ part1s,
                                               float* __restrict__ part1q) {
    __shared__ __align__(16) float sX[3][32][36];   // 13,824 B (pad 4: 2-way max)
    __shared__ float sW[16][76];                    //  4,864 B
    __shared__ float sS[224], sQ[224];              //  1,792 B
    const int ocg = blockIdx.x;
    const int b = blockIdx.y;
    const int oc0 = ocg * 16;
    const int tid = threadIdx.x;
    for (int j = tid; j < 3072; j += 256) {
        int ic = j >> 10, rem = j & 1023;
        sX[ic][rem >> 5][rem & 31] = x[b * 3072 + j];
    }
    for (int j = tid; j < 16 * 75; j += 256) {
        sW[j / 75][j % 75] = w[oc0 * 75 + j];
    }
    __syncthreads();
    const bool act = tid < 224;
    const int oc_l = tid / 14, oy = tid % 14;
    float acc[14];
#pragma unroll
    for (int j = 0; j < 14; ++j) acc[j] = 0.f;
    if (act) {
        const float* wr = &sW[oc_l][0];
#pragma unroll
        for (int ic = 0; ic < 3; ++ic) {
#pragma unroll
            for (int ky = 0; ky < 5; ++ky) {
                const float* xr = &sX[ic][2 * oy + ky][0];
                float row[32];
#pragma unroll
                for (int q = 0; q < 8; ++q) {
                    float4 v = *reinterpret_cast<const float4*>(xr + q * 4);
                    row[q * 4 + 0] = v.x; row[q * 4 + 1] = v.y;
                    row[q * 4 + 2] = v.z; row[q * 4 + 3] = v.w;
                }
                float w0 = wr[ic * 25 + ky * 5 + 0];
                float w1 = wr[ic * 25 + ky * 5 + 1];
                float w2 = wr[ic * 25 + ky * 5 + 2];
                float w3 = wr[ic * 25 + ky * 5 + 3];
                float w4 = wr[ic * 25 + ky * 5 + 4];
#pragma unroll
                for (int ox = 0; ox < 14; ++ox) {
                    float s = acc[ox];
                    s = fmaf(row[2 * ox + 0], w0, s);
                    s = fmaf(row[2 * ox + 1], w1, s);
                    s = fmaf(row[2 * ox + 2], w2, s);
                    s = fmaf(row[2 * ox + 3], w3, s);
                    s = fmaf(row[2 * ox + 4], w4, s);
                    acc[ox] = s;
                }
            }
        }
        float* out = h + ((size_t)(b * AA + oc0 + oc_l) * 14 + oy) * 14;
#pragma unroll
        for (int q = 0; q < 7; ++q)
            *reinterpret_cast<float2*>(out + q * 2) = make_float2(acc[q * 2], acc[q * 2 + 1]);
        float s_th = 0.f, q_th = 0.f;
#pragma unroll
        for (int ox = 0; ox < 14; ++ox) { s_th += acc[ox]; q_th = fmaf(acc[ox], acc[ox], q_th); }
        sS[tid] = s_th; sQ[tid] = q_th;
    }
    __syncthreads();
    if (tid < 16) {
        float s = 0.f, q = 0.f;
#pragma unroll
        for (int r = 0; r < 14; ++r) { s += sS[tid * 14 + r]; q += sQ[tid * 14 + r]; }
        part1s[(oc0 + tid) * NB + b] = s;
        part1q[(oc0 + tid) * NB + b] = q;
    }
}

// ---------------- block reduce helper (s, s2); requires 256 threads ----------------
__device__ __forceinline__ void blk_reduce2(float& s, float& s2, int tid) {
#pragma unroll
    for (int o = 32; o > 0; o >>= 1) { s += __shfl_down(s, o); s2 += __shfl_down(s2, o); }
    __shared__ float ls[4], lq[4];
    int lane = tid & 63, wid = tid >> 6;
    if (lane == 0) { ls[wid] = s; lq[wid] = s2; }
    __syncthreads();
    if (tid == 0) {
        s = ls[0] + ls[1] + ls[2] + ls[3];
        s2 = lq[0] + lq[1] + lq[2] + lq[3];
    }
}

// ---------------- bn1 reduce: 128 blocks (one per channel) -> coefficients ----------
__global__ void k_bnred1(const float* __restrict__ part1s, const float* __restrict__ part1q,
                         const float* __restrict__ g, const float* __restrict__ be,
                         float* __restrict__ bn1) {
    int c = blockIdx.x;
    int tid = threadIdx.x;
    float s = (tid < NB) ? part1s[c * NB + tid] : 0.f;
    float s2 = (tid < NB) ? part1q[c * NB + tid] : 0.f;
    blk_reduce2(s, s2, tid);
    if (tid == 0) {
        const float n = (float)(NB * 196);
        float mu = s / n;
        float var = s2 / n - mu * mu;
        float sc = g[c] * rsqrtf(var + 1e-5f);
        bn1[c] = sc;
        bn1[AA + c] = be[c] - mu * sc;
    }
}

// ---------------- merged prepw + im2col (bn1 coefficients from global) ----------------
__global__ void k_pim(const float* __restrict__ w, const float* __restrict__ h,
                      const float* __restrict__ bn1,
                      unsigned short* __restrict__ Ah, unsigned short* __restrict__ Al,
                      unsigned short* __restrict__ Bh, unsigned short* __restrict__ Bl) {
    const int blk = blockIdx.x;
    const int tid = threadIdx.x;
    if (blk < 324) {
        int t = blk * 256 + tid;                  // exactly MG*144 items
        int row = t / (KG / 8), seg = t % (KG / 8);
        alignas(16) unsigned short hi[8], lo[8];
        if (row < CH2) {
            const float* src = w + (size_t)row * KG + seg * 8;
#pragma unroll
            for (int j = 0; j < 8; ++j) {
                float v = src[j];
                unsigned short hh = f2bf(v);
                hi[j] = hh;
                lo[j] = f2bf(v - bf2f(hh));
            }
        } else {
#pragma unroll
            for (int j = 0; j < 8; ++j) { hi[j] = 0; lo[j] = 0; }
        }
        *reinterpret_cast<uint4*>(Ah + (size_t)row * KG + seg * 8) = *reinterpret_cast<const uint4*>(hi);
        *reinterpret_cast<uint4*>(Al + (size_t)row * KG + seg * 8) = *reinterpret_cast<const uint4*>(lo);
        return;
    }
    __shared__ float sBn1[2 * AA];
    sBn1[tid] = bn1[tid];     // 256 == 2*AA
    __syncthreads();
    int t = (blk - 324) * 256 + tid;              // exactly NG*144 items
    int n = t / (KG / 8), seg = t % (KG / 8);
    int b = n / 36, xy = n % 36;
    int oy = xy / 6, ox = xy % 6;
    const float* hb = h + (size_t)b * (AA * 196) + (2 * oy) * 14 + 2 * ox;
    alignas(16) unsigned short hi[8], lo[8];
#pragma unroll
    for (int j = 0; j < 8; ++j) {
        int k = seg * 8 + j;
        int ic = k / 9, kk = k - ic * 9;
        int ky = kk / 3, kx = kk - ky * 3;
        float v = hb[ic * 196 + ky * 14 + kx];
        v = fmaxf(fmaf(v, sBn1[ic], sBn1[AA + ic]), 0.f);
        unsigned short hh = f2bf(v);
        hi[j] = hh;
        lo[j] = f2bf(v - bf2f(hh));
    }
    *reinterpret_cast<uint4*>(Bh + (size_t)n * KG + seg * 8) = *reinterpret_cast<const uint4*>(hi);
    *reinterpret_cast<uint4*>(Bl + (size_t)n * KG + seg * 8) = *reinterpret_cast<const uint4*>(lo);
}

// ---------------- conv2 GEMM (pipelined, XCD-swizzled) + bn2-stats epilogue ----------
// part2 layout (floats): [0,2304) pose s [g][y], [2304,4608) pose s2,
//                        [4608,6912) a s [ch][y], [6912,9216) a s2.
__global__ __launch_bounds__(256, 4) void k_gemm(const unsigned short* __restrict__ Ah,
                                                 const unsigned short* __restrict__ Al,
                                                 const unsigned short* __restrict__ Bh,
                                                 const unsigned short* __restrict__ Bl,
                                                 float* __restrict__ pcT,
                                                 float* __restrict__ part2) {
    __shared__ alignas(16) unsigned short sAh[64][44], sAl[64][44];
    __shared__ alignas(16) unsigned short sBh[64][44], sBl[64][44];
    __shared__ float sRed[128];
    const int s = blockIdx.x;
    const int k8 = s & 7, j = s >> 3;
    const int jm = j / 9;
    const int y = k8 + 8 * jm;
    const int xg = j - 9 * jm;
    const int oc0 = xg * 64;
    const int n0 = y * 64;
    const int tid = threadIdx.x;
    const int lane = tid & 63, wv = tid >> 6;
    const int wm = wv >> 1, wn = wv & 1;
    const int quad = lane >> 4, r16 = lane & 15;
    const int srow = tid >> 2, sseg = tid & 3;

    facc4 acc[2][2] = {};
    const size_t gA = (size_t)(oc0 + srow) * KG + sseg * 8;
    const size_t gB = (size_t)(n0 + srow) * KG + sseg * 8;

    // LOAD(0)
    uint4 vAh = *reinterpret_cast<const uint4*>(Ah + gA);
    uint4 vAl = *reinterpret_cast<const uint4*>(Al + gA);
    uint4 vBh = *reinterpret_cast<const uint4*>(Bh + gB);
    uint4 vBl = *reinterpret_cast<const uint4*>(Bl + gB);

    for (int ks = 0; ks < KG / 32; ++ks) {
        __syncthreads();   // previous compute done reading LDS
        *reinterpret_cast<uint4*>(&sAh[srow][sseg * 8]) = vAh;
        *reinterpret_cast<uint4*>(&sAl[srow][sseg * 8]) = vAl;
        *reinterpret_cast<uint4*>(&sBh[srow][sseg * 8]) = vBh;
        *reinterpret_cast<uint4*>(&sBl[srow][sseg * 8]) = vBl;
        __syncthreads();
        // LOAD(ks+1): lands during compute
        if (ks + 1 < KG / 32) {
            const int k0n = (ks + 1) * 32;
            vAh = *reinterpret_cast<const uint4*>(Ah + gA + k0n);
            vAl = *reinterpret_cast<const uint4*>(Al + gA + k0n);
            vBh = *reinterpret_cast<const uint4*>(Bh + gB + k0n);
            vBl = *reinterpret_cast<const uint4*>(Bl + gB + k0n);
        }
        // COMPUTE(ks)
        bfrag8 ah[2], al[2], bh[2], bl[2];
#pragma unroll
        for (int i = 0; i < 2; ++i) {
            ah[i] = *reinterpret_cast<const bfrag8*>(&sAh[wm * 32 + i * 16 + r16][quad * 8]);
            al[i] = *reinterpret_cast<const bfrag8*>(&sAl[wm * 32 + i * 16 + r16][quad * 8]);
            bh[i] = *reinterpret_cast<const bfrag8*>(&sBh[wn * 32 + i * 16 + r16][quad * 8]);
            bl[i] = *reinterpret_cast<const bfrag8*>(&sBl[wn * 32 + i * 16 + r16][quad * 8]);
        }
#pragma unroll
        for (int i = 0; i < 2; ++i)
#pragma unroll
            for (int jj = 0; jj < 2; ++jj) {
                acc[i][jj] = __builtin_amdgcn_mfma_f32_16x16x32_bf16(ah[i], bh[jj], acc[i][jj], 0, 0, 0);
                acc[i][jj] = __builtin_amdgcn_mfma_f32_16x16x32_bf16(ah[i], bl[jj], acc[i][jj], 0, 0, 0);
                acc[i][jj] = __builtin_amdgcn_mfma_f32_16x16x32_bf16(al[i], bh[jj], acc[i][jj], 0, 0, 0);
            }
    }
    // store
#pragma unroll
    for (int i = 0; i < 2; ++i) {
        int oc_base = oc0 + wm * 32 + i * 16 + quad * 4;
        if (oc_base >= CH2) continue;
#pragma unroll
        for (int jj = 0; jj < 2; ++jj) {
            int n = n0 + wn * 32 + jj * 16 + r16;
            *reinterpret_cast<facc4*>(pcT + (size_t)n * CH2 + oc_base) = acc[i][jj];
        }
    }
    // ---- bn2-stats partials ----
    if (xg < 8) {
        float ps[2], pq[2];
#pragma unroll
        for (int i = 0; i < 2; ++i) {
            float sv = 0.f, qv = 0.f;
#pragma unroll
            for (int jj = 0; jj < 2; ++jj)
#pragma unroll
                for (int comp = 0; comp < 4; ++comp) {
                    float v = acc[i][jj][comp];
                    sv += v; qv = fmaf(v, v, qv);
                }
#pragma unroll
            for (int o = 32; o > 0; o >>= 1) { sv += __shfl_down(sv, o); qv += __shfl_down(qv, o); }
            ps[i] = sv; pq[i] = qv;
        }
        if (lane == 0) {
#pragma unroll
            for (int i = 0; i < 2; ++i) { sRed[wv * 4 + i * 2 + 0] = ps[i]; sRed[wv * 4 + i * 2 + 1] = pq[i]; }
        }
        __syncthreads();
        if (tid < 8) {
            int wm_ = tid >> 2, i_ = (tid >> 1) & 1, sel = tid & 1;
            float v = sRed[(2 * wm_) * 4 + i_ * 2 + sel] + sRed[(2 * wm_ + 1) * 4 + i_ * 2 + sel];
            int g = xg * 4 + wm_ * 2 + i_;
            part2[sel * 2304 + g * 72 + y] = v;
        }
    } else {
        if (wm == 0) {
#pragma unroll
            for (int i = 0; i < 2; ++i)
#pragma unroll
                for (int comp = 0; comp < 4; ++comp) {
                    float v0 = acc[i][0][comp], v1 = acc[i][1][comp];
                    float sv = v0 + v1;
                    float qv = fmaf(v0, v0, v1 * v1);
#pragma unroll
                    for (int o = 8; o > 0; o >>= 1) {
                        sv += __shfl_down(sv, o, 16);
                        qv += __shfl_down(qv, o, 16);
                    }
                    if (r16 == 0) {
                        int idx = ((wv * 4 + quad) * 2 + i) * 4 + comp;   // 0..63
                        sRed[idx] = sv;
                        sRed[64 + idx] = qv;
                    }
                }
        }
        __syncthreads();
        if (tid < 64) {
            int ch = tid >> 1, sel = tid & 1;
            int i_ = ch >> 4, rem = ch & 15, quad_ = rem >> 2, comp_ = rem & 3;
            int base = sel * 64;
            float v = sRed[base + ((0 * 4 + quad_) * 2 + i_) * 4 + comp_] +
                      sRed[base + ((1 * 4 + quad_) * 2 + i_) * 4 + comp_];
            part2[4608 + sel * 2304 + ch * 72 + y] = v;
        }
    }
}

// ---------------- digamma (args always >= 1.0 here) ----------------
__device__ __forceinline__ float digammaf_(float x) {
    float r = 0.f;
    while (x < 6.f) { r -= 1.f / x; x += 1.f; }
    float xi = 1.f / x;
    float xi2 = xi * xi;
    return r + logf(x) - 0.5f * xi -
           xi2 * (0.0833333333f - xi2 * (0.0083333333f - xi2 * 0.0039682540f));
}

// ---------------- merged routing: bn2 finalize + expectations + update + stats --------
// grid 768: block = (b = blk/6, seg = blk%6); 192 n-rows per block (3 iters of 64).
// 640 threads = 10 waves; wave c owns class c. 3 blocks/CU co-resident.
template <int FIRST>
__global__ __launch_bounds__(640) void k_routed(
    const float* __restrict__ pcT, const float* __restrict__ part2,
    const float* __restrict__ bna_g, const float* __restrict__ bna_b,
    const float* __restrict__ bnp_g, const float* __restrict__ bnp_b,
    const float* __restrict__ Wij,
    const float* __restrict__ S0i, const float* __restrict__ S1i, const float* __restrict__ S2i,
    float* __restrict__ S0o, float* __restrict__ S1o, float* __restrict__ S2o) {
    const int b = blockIdx.x / NSEG, seg = blockIdx.x % NSEG;
    const int tid = threadIdx.x;
    const int c = tid >> 6, lane = tid & 63;
    __shared__ float sLnp[CC][66];
    __shared__ float sBn2[128];
    __shared__ __align__(16) float sP[64][20];
    __shared__ float sA[64];
    __shared__ float sM[CC][16], sGq[CC][16], sBase[CC];
    if (tid < 64) {
        if (tid < 32) {
            int i = tid;
            float s = 0.f, s2 = 0.f;
            for (int yy = 0; yy < 72; ++yy) { s += part2[i * 72 + yy]; s2 += part2[2304 + i * 72 + yy]; }
            const float n = (float)(NB * DD * 36);
            float mu = s / n, var = s2 / n - mu * mu;
            float sc = bnp_g[i] * rsqrtf(var + 1e-5f);
            sBn2[i] = sc; sBn2[32 + i] = bnp_b[i] - mu * sc;
        } else {
            int ch = tid - 32;
            float s = 0.f, s2 = 0.f;
            for (int yy = 0; yy < 72; ++yy) { s += part2[4608 + ch * 72 + yy]; s2 += part2[6912 + ch * 72 + yy]; }
            const float n = (float)(NB * 36);
            float mu = s / n, var = s2 / n - mu * mu;
            float sc = bna_g[ch] * rsqrtf(var + 1e-5f);
            sBn2[64 + ch] = sc; sBn2[96 + ch] = bna_b[ch] - mu * sc;
        }
    }
    if (!FIRST && tid < 160) {
        int cc = tid >> 4, d = tid & 15;
        int bc = b * CC + cc;
        float njraw = 0.f;
#pragma unroll
        for (int sg = 0; sg < NSEG; ++sg) njraw += S0i[sg * (NB * CC) + bc];
        float nj = njraw + 1e-8f;
        float kappa = 1.f + nj;
        float nu = 17.f + nj;
        float s1 = 0.f, s2v = 0.f;
#pragma unroll
        for (int sg = 0; sg < NSEG; ++sg) {
            s1 += S1i[sg * (NB * CC * 16) + bc * 16 + d];
            s2v += S2i[sg * (NB * CC * 16) + bc * 16 + d];
        }
        float xbar = s1 / nj;
        float sig = (s2v - 2.f * xbar * s1 + xbar * xbar * njraw) / nj;
        float Psi = 1.f + nj * sig + (nj / kappa) * xbar * xbar;
        sM[cc][d] = nj * xbar / kappa;
        sGq[cc][d] = 0.5f * nu / Psi;
        float term = digammaf_(0.5f * (nu + 1.f - (float)(d + 1))) - logf(Psi);
#pragma unroll
        for (int o = 8; o > 0; o >>= 1) term += __shfl_down(term, o, 16);
        if (d == 0) {
            float asum = 0.f;
#pragma unroll
            for (int k = 0; k < CC; ++k) {
                float t = 0.f;
#pragma unroll
                for (int sg = 0; sg < NSEG; ++sg) t += S0i[sg * (NB * CC) + b * CC + k];
                asum += 1.f + t + 1e-8f;
            }
            float elnlam = 16.f * 0.69314718056f + term;
            float elnpi = digammaf_(1.f + nj) - digammaf_(asum);
            float lb = elnpi + 0.5f * elnlam;
            sBase[cc] = lb - 8.f * 1.83787706641f - 8.f / kappa;
        }
    }
    __syncthreads();
    float mc[16], Gc[16], basec = 0.f;
    if (!FIRST) {
#pragma unroll
        for (int d = 0; d < 16; ++d) { mc[d] = sM[c][d]; Gc[d] = sGq[c][d]; }
        basec = sBase[c];
    }
    float s0 = 0.f, s1[16], s2[16];
#pragma unroll
    for (int d = 0; d < 16; ++d) { s1[d] = 0.f; s2[d] = 0.f; }

#pragma unroll 1
    for (int it = 0; it < 3; ++it) {
        if (tid < 256) {
            int r = tid >> 2, q = tid & 3;
            int n = seg * 192 + it * 64 + r;
            int i = n / 36, xy = n - i * 36;
            int row = b * 36 + xy;
            float4 v = *reinterpret_cast<const float4*>(pcT + (size_t)row * CH2 + i * 16 + q * 4);
            float psc = sBn2[i], psh = sBn2[32 + i];
            v.x = fmaf(v.x, psc, psh); v.y = fmaf(v.y, psc, psh);
            v.z = fmaf(v.z, psc, psh); v.w = fmaf(v.w, psc, psh);
            *reinterpret_cast<float4*>(&sP[r][q * 4]) = v;
        } else if (tid < 320) {
            int r = tid - 256;
            int n = seg * 192 + it * 64 + r;
            int i = n / 36, xy = n - i * 36;
            int row = b * 36 + xy;
            float va = fmaf(pcT[(size_t)row * CH2 + BB * DD + i], sBn2[64 + i], sBn2[96 + i]);
            sA[r] = 1.f / (1.f + expf(-va));
        }
        __syncthreads();   // A: sP/sA ready
        const int n = seg * 192 + it * 64 + lane;
        const int i = n / 36, xy = n - i * 36;
        const float4* wp = reinterpret_cast<const float4*>(Wij + (((size_t)i * CC + c) * 36 + xy) * 16);
        alignas(16) float P[16], W[16];
        *reinterpret_cast<float4*>(&P[0])  = *reinterpret_cast<const float4*>(&sP[lane][0]);
        *reinterpret_cast<float4*>(&P[4])  = *reinterpret_cast<const float4*>(&sP[lane][4]);
        *reinterpret_cast<float4*>(&P[8])  = *reinterpret_cast<const float4*>(&sP[lane][8]);
        *reinterpret_cast<float4*>(&P[12]) = *reinterpret_cast<const float4*>(&sP[lane][12]);
        *reinterpret_cast<float4*>(&W[0])  = wp[0];
        *reinterpret_cast<float4*>(&W[4])  = wp[1];
        *reinterpret_cast<float4*>(&W[8])  = wp[2];
        *reinterpret_cast<float4*>(&W[12]) = wp[3];
        float V[16];
#pragma unroll
        for (int p = 0; p < 4; ++p)
#pragma unroll
            for (int r = 0; r < 4; ++r)
                V[p * 4 + r] = W[p * 4 + 0] * P[0 + r] + W[p * 4 + 1] * P[4 + r] +
                               W[p * 4 + 2] * P[8 + r] + W[p * 4 + 3] * P[12 + r];
        float av = sA[lane];
        float wgt;
        if (FIRST) {
            wgt = 0.1f * av;
            __syncthreads();   // B: all reads of sP/sA done before next stage
        } else {
            float q = 0.f;
#pragma unroll
            for (int d = 0; d < 16; ++d) {
                float dm = V[d] - mc[d];
                q = fmaf(dm * dm, Gc[d], q);
            }
            float lnp = basec - q;
            sLnp[c][lane] = lnp;
            __syncthreads();   // B: sLnp ready; sP/sA reads done
            float mx = -1e30f;
#pragma unroll
            for (int cc = 0; cc < CC; ++cc) mx = fmaxf(mx, sLnp[cc][lane]);
            float ssum = 0.f;
#pragma unroll
            for (int cc = 0; cc < CC; ++cc) ssum += expf(sLnp[cc][lane] - mx);
            wgt = expf(lnp - mx) / ssum * av;
        }
        s0 += wgt;
#pragma unroll
        for (int d = 0; d < 16; ++d) {
            float wv = wgt * V[d];
            s1[d] += wv;
            s2[d] = fmaf(wv, V[d], s2[d]);
        }
    }
#pragma unroll
    for (int o = 32; o > 0; o >>= 1) {
        s0 += __shfl_down(s0, o);
#pragma unroll
        for (int k = 0; k < 16; ++k) {
            s1[k] += __shfl_down(s1[k], o);
            s2[k] += __shfl_down(s2[k], o);
        }
    }
    if (lane == 0) {
        int idx = seg * (NB * CC) + b * CC + c;
        S0o[idx] = s0;
#pragma unroll
        for (int k = 0; k < 16; ++k) { S1o[idx * 16 + k] = s1[k]; S2o[idx * 16 + k] = s2[k]; }
    }
}

// ---------------- final: expectations (logits) inline + BN over batch + sigmoid -------
__global__ void k_final2(const float* __restrict__ S0p, const float* __restrict__ S1p,
                         const float* __restrict__ S2p, float* __restrict__ out) {
    int c = blockIdx.x;      // 10 blocks
    int b = threadIdx.x;     // 128 threads
    int bc = b * CC + c;
    float njraw = 0.f;
#pragma unroll
    for (int sg = 0; sg < NSEG; ++sg) njraw += S0p[sg * (NB * CC) + bc];
    float nj = njraw + 1e-8f;
    float asum = 0.f;
#pragma unroll
    for (int k = 0; k < CC; ++k) {
        float t = 0.f;
#pragma unroll
        for (int sg = 0; sg < NSEG; ++sg) t += S0p[sg * (NB * CC) + b * CC + k];
        asum += 1.f + t + 1e-8f;
    }
    float kappa = 1.f + nj;
    float nu = 17.f + nj;
    float elnlam = 16.f * 0.69314718056f;
    for (int d = 0; d < 16; ++d) {
        float s1 = 0.f, s2v = 0.f;
#pragma unroll
        for (int sg = 0; sg < NSEG; ++sg) {
            s1 += S1p[sg * (NB * CC * 16) + bc * 16 + d];
            s2v += S2p[sg * (NB * CC * 16) + bc * 16 + d];
        }
        float xbar = s1 / nj;
        float sig = (s2v - 2.f * xbar * s1 + xbar * xbar * njraw) / nj;
        float Psi = 1.f + nj * sig + (nj / kappa) * xbar * xbar;
        elnlam += digammaf_(0.5f * (nu + 1.f - (float)(d + 1))) - logf(Psi);
    }
    float elnpi = digammaf_(1.f + nj) - digammaf_(asum);
    float v = elnpi + 0.5f * elnlam;
    float s = v, s2 = v * v;
#pragma unroll
    for (int o = 32; o > 0; o >>= 1) { s += __shfl_down(s, o); s2 += __shfl_down(s2, o); }
    __shared__ float ls[2], lq[2];
    int lane = b & 63, wid = b >> 6;
    if (lane == 0) { ls[wid] = s; lq[wid] = s2; }
    __syncthreads();
    float mu = (ls[0] + ls[1]) * (1.f / 128.f);
    float var = (lq[0] + lq[1]) * (1.f / 128.f) - mu * mu;
    out[b * CC + c] = 1.f / (1.f + expf(-(v - mu) * rsqrtf(var + 1e-5f)));
}

extern "C" void kernel_launch(void* const* d_in, const int* in_sizes, int n_in,
                              void* d_out, int out_size, void* d_ws, size_t ws_size,
                              hipStream_t stream) {
    (void)in_sizes; (void)n_in; (void)out_size; (void)ws_size;
    const float* x       = (const float*)d_in[0];
    const float* conv1_w = (const float*)d_in[1];
    const float* bn1_g   = (const float*)d_in[2];
    const float* bn1_b   = (const float*)d_in[3];
    const float* prim_w  = (const float*)d_in[4];
    const float* bna_g   = (const float*)d_in[5];
    const float* bna_b   = (const float*)d_in[6];
    const float* bnp_g   = (const float*)d_in[7];
    const float* bnp_b   = (const float*)d_in[8];
    const float* Wij     = (const float*)d_in[9];

    float* ws = (float*)d_ws;
    float* h   = ws;                                          // 3,211,264 f32
    float* pcT = ws + 3211264;                                // 2,506,752 f32 [4608][544]
    unsigned short* Bh = (unsigned short*)(ws + 5718016);     // 5,308,416 bf16
    unsigned short* Bl = (unsigned short*)(ws + 8372224);     // 5,308,416 bf16
    unsigned short* Ahp = (unsigned short*)(ws + 11026432);   //   663,552 bf16
    unsigned short* Alp = (unsigned short*)(ws + 11358208);   //   663,552 bf16
    float* bn1    = ws + 11689984;   // 256
    float* S0a    = ws + 11690368;   // 7,680
    float* S1a    = ws + 11698048;   // 122,880
    float* S2a    = ws + 11820928;   // 122,880
    float* S0b    = ws + 11943808;   // 7,680
    float* S1b    = ws + 11951488;   // 122,880
    float* S2b    = ws + 12074368;   // 122,880
    float* part1s = ws + 12197248;   // 16,384
    float* part1q = ws + 12213632;   // 16,384
    float* part2  = ws + 12230016;   // 9,216
    float* out    = (float*)d_out;

    k_conv1<<<dim3(8, 128), 256, 0, stream>>>(x, conv1_w, h, part1s, part1q);
    k_bnred1<<<128, 256, 0, stream>>>(part1s, part1q, bn1_g, bn1_b, bn1);
    k_pim<<<2916, 256, 0, stream>>>(prim_w, h, bn1, Ahp, Alp, Bh, Bl);
    k_gemm<<<648, 256, 0, stream>>>(Ahp, Alp, Bh, Bl, pcT, part2);

    // routing: iter0 (R = 1/C) -> A; iter1 (expect from A) -> B; iter2 (expect from B) -> A
    k_routed<1><<<NB * NSEG, 640, 0, stream>>>(pcT, part2, bna_g, bna_b, bnp_g, bnp_b, Wij,
                                               S0a, S1a, S2a, S0a, S1a, S2a);
    k_routed<0><<<NB * NSEG, 640, 0, stream>>>(pcT, part2, bna_g, bna_b, bnp_g, bnp_b, Wij,
                                               S0a, S1a, S2a, S0b, S1b, S2b);
    k_routed<0><<<NB * NSEG, 640, 0, stream>>>(pcT, part2, bna_g, bna_b, bnp_g, bnp_b, Wij,
                                               S0b, S1b, S2b, S0a, S1a, S2a);
    k_final2<<<10, 128, 0, stream>>>(S0a, S1a, S2a, out);
}

// Round 20
// 179.891 us; speedup vs baseline: 1.4549x; 1.4549x over previous
//
#include <hip/hip_runtime.h>
#include <hip/hip_bf16.h>

// Problem constants
#define NB 128     // batch
#define AA 128     // conv1 out channels
#define BB 32      // capsule types
#define CC 10      // classes
#define KK 6       // primary grid
#define DD 16      // pose dim
#define NN 1152    // B*K*K
#define H1 14      // conv1 out spatial
#define CH2 544    // B*D+B
#define NG 4608    // GEMM N = NB*36
#define KG 1152    // GEMM K = 128*9
#define MG 576     // GEMM M padded (544 -> 9*64)

typedef short bfrag8 __attribute__((ext_vector_type(8)));   // 8 bf16 (4 VGPRs)
typedef float facc4 __attribute__((ext_vector_type(4)));    // 4 fp32 acc

__device__ __forceinline__ unsigned short f2bf(float f) {   // RNE f32->bf16
    unsigned u = __float_as_uint(f);
    u += 0x7FFF + ((u >> 16) & 1);
    return (unsigned short)(u >> 16);
}
__device__ __forceinline__ float bf2f(unsigned short s) {
    return __uint_as_float(((unsigned)s) << 16);
}

// ---------------- conv1: block = (16-oc group, b); full image in LDS ----------------
__global__ __launch_bounds__(256) void k_conv1(const float* __restrict__ x,
                                               const float* __restrict__ w,
                                               float* __restrict__ h,
                                               float* __restrict__ part1s,
                                               float* __restrict__ part1q) {
    __shared__ __align__(16) float sX[3][32][36];   // 13,824 B
    __shared__ float sW[16][76];                    //  4,864 B
    __shared__ float sS[224], sQ[224];              //  1,792 B
    const int ocg = blockIdx.x;
    const int b = blockIdx.y;
    const int oc0 = ocg * 16;
    const int tid = threadIdx.x;
    for (int j = tid; j < 3072; j += 256) {
        int ic = j >> 10, rem = j & 1023;
        sX[ic][rem >> 5][rem & 31] = x[b * 3072 + j];
    }
    for (int j = tid; j < 16 * 75; j += 256) {
        sW[j / 75][j % 75] = w[oc0 * 75 + j];
    }
    __syncthreads();
    const bool act = tid < 224;
    const int oc_l = tid / 14, oy = tid % 14;
    float acc[14];
#pragma unroll
    for (int j = 0; j < 14; ++j) acc[j] = 0.f;
    if (act) {
        const float* wr = &sW[oc_l][0];
#pragma unroll
        for (int ic = 0; ic < 3; ++ic) {
#pragma unroll
            for (int ky = 0; ky < 5; ++ky) {
                const float* xr = &sX[ic][2 * oy + ky][0];
                float row[32];
#pragma unroll
                for (int q = 0; q < 8; ++q) {
                    float4 v = *reinterpret_cast<const float4*>(xr + q * 4);
                    row[q * 4 + 0] = v.x; row[q * 4 + 1] = v.y;
                    row[q * 4 + 2] = v.z; row[q * 4 + 3] = v.w;
                }
                float w0 = wr[ic * 25 + ky * 5 + 0];
                float w1 = wr[ic * 25 + ky * 5 + 1];
                float w2 = wr[ic * 25 + ky * 5 + 2];
                float w3 = wr[ic * 25 + ky * 5 + 3];
                float w4 = wr[ic * 25 + ky * 5 + 4];
#pragma unroll
                for (int ox = 0; ox < 14; ++ox) {
                    float s = acc[ox];
                    s = fmaf(row[2 * ox + 0], w0, s);
                    s = fmaf(row[2 * ox + 1], w1, s);
                    s = fmaf(row[2 * ox + 2], w2, s);
                    s = fmaf(row[2 * ox + 3], w3, s);
                    s = fmaf(row[2 * ox + 4], w4, s);
                    acc[ox] = s;
                }
            }
        }
        float* out = h + ((size_t)(b * AA + oc0 + oc_l) * 14 + oy) * 14;
#pragma unroll
        for (int q = 0; q < 7; ++q)
            *reinterpret_cast<float2*>(out + q * 2) = make_float2(acc[q * 2], acc[q * 2 + 1]);
        float s_th = 0.f, q_th = 0.f;
#pragma unroll
        for (int ox = 0; ox < 14; ++ox) { s_th += acc[ox]; q_th = fmaf(acc[ox], acc[ox], q_th); }
        sS[tid] = s_th; sQ[tid] = q_th;
    }
    __syncthreads();
    if (tid < 16) {
        float s = 0.f, q = 0.f;
#pragma unroll
        for (int r = 0; r < 14; ++r) { s += sS[tid * 14 + r]; q += sQ[tid * 14 + r]; }
        part1s[(oc0 + tid) * NB + b] = s;
        part1q[(oc0 + tid) * NB + b] = q;
    }
}

// ---------------- block reduce helper (s, s2); requires 256 threads ----------------
__device__ __forceinline__ void blk_reduce2(float& s, float& s2, int tid) {
#pragma unroll
    for (int o = 32; o > 0; o >>= 1) { s += __shfl_down(s, o); s2 += __shfl_down(s2, o); }
    __shared__ float ls[4], lq[4];
    int lane = tid & 63, wid = tid >> 6;
    if (lane == 0) { ls[wid] = s; lq[wid] = s2; }
    __syncthreads();
    if (tid == 0) {
        s = ls[0] + ls[1] + ls[2] + ls[3];
        s2 = lq[0] + lq[1] + lq[2] + lq[3];
    }
}

// ---------------- bn1 reduce: 128 blocks (one per channel) -> coefficients ----------
__global__ void k_bnred1(const float* __restrict__ part1s, const float* __restrict__ part1q,
                         const float* __restrict__ g, const float* __restrict__ be,
                         float* __restrict__ bn1) {
    int c = blockIdx.x;
    int tid = threadIdx.x;
    float s = (tid < NB) ? part1s[c * NB + tid] : 0.f;
    float s2 = (tid < NB) ? part1q[c * NB + tid] : 0.f;
    blk_reduce2(s, s2, tid);
    if (tid == 0) {
        const float n = (float)(NB * 196);
        float mu = s / n;
        float var = s2 / n - mu * mu;
        float sc = g[c] * rsqrtf(var + 1e-5f);
        bn1[c] = sc;
        bn1[AA + c] = be[c] - mu * sc;
    }
}

// ---------------- merged prepw + im2col (bn1 coefficients from global) ----------------
__global__ void k_pim(const float* __restrict__ w, const float* __restrict__ h,
                      const float* __restrict__ bn1,
                      unsigned short* __restrict__ Ah, unsigned short* __restrict__ Al,
                      unsigned short* __restrict__ Bh, unsigned short* __restrict__ Bl) {
    const int blk = blockIdx.x;
    const int tid = threadIdx.x;
    if (blk < 324) {
        int t = blk * 256 + tid;
        int row = t / (KG / 8), seg = t % (KG / 8);
        alignas(16) unsigned short hi[8], lo[8];
        if (row < CH2) {
            const float* src = w + (size_t)row * KG + seg * 8;
#pragma unroll
            for (int j = 0; j < 8; ++j) {
                float v = src[j];
                unsigned short hh = f2bf(v);
                hi[j] = hh;
                lo[j] = f2bf(v - bf2f(hh));
            }
        } else {
#pragma unroll
            for (int j = 0; j < 8; ++j) { hi[j] = 0; lo[j] = 0; }
        }
        *reinterpret_cast<uint4*>(Ah + (size_t)row * KG + seg * 8) = *reinterpret_cast<const uint4*>(hi);
        *reinterpret_cast<uint4*>(Al + (size_t)row * KG + seg * 8) = *reinterpret_cast<const uint4*>(lo);
        return;
    }
    __shared__ float sBn1[2 * AA];
    sBn1[tid] = bn1[tid];
    __syncthreads();
    int t = (blk - 324) * 256 + tid;
    int n = t / (KG / 8), seg = t % (KG / 8);
    int b = n / 36, xy = n % 36;
    int oy = xy / 6, ox = xy % 6;
    const float* hb = h + (size_t)b * (AA * 196) + (2 * oy) * 14 + 2 * ox;
    alignas(16) unsigned short hi[8], lo[8];
#pragma unroll
    for (int j = 0; j < 8; ++j) {
        int k = seg * 8 + j;
        int ic = k / 9, kk = k - ic * 9;
        int ky = kk / 3, kx = kk - ky * 3;
        float v = hb[ic * 196 + ky * 14 + kx];
        v = fmaxf(fmaf(v, sBn1[ic], sBn1[AA + ic]), 0.f);
        unsigned short hh = f2bf(v);
        hi[j] = hh;
        lo[j] = f2bf(v - bf2f(hh));
    }
    *reinterpret_cast<uint4*>(Bh + (size_t)n * KG + seg * 8) = *reinterpret_cast<const uint4*>(hi);
    *reinterpret_cast<uint4*>(Bl + (size_t)n * KG + seg * 8) = *reinterpret_cast<const uint4*>(lo);
}

// ---------------- conv2 GEMM (pipelined, XCD-swizzled) + bn2-stats epilogue ----------
__global__ __launch_bounds__(256, 4) void k_gemm(const unsigned short* __restrict__ Ah,
                                                 const unsigned short* __restrict__ Al,
                                                 const unsigned short* __restrict__ Bh,
                                                 const unsigned short* __restrict__ Bl,
                                                 float* __restrict__ pcT,
                                                 float* __restrict__ part2) {
    __shared__ alignas(16) unsigned short sAh[64][44], sAl[64][44];
    __shared__ alignas(16) unsigned short sBh[64][44], sBl[64][44];
    __shared__ float sRed[128];
    const int s = blockIdx.x;
    const int k8 = s & 7, j = s >> 3;
    const int jm = j / 9;
    const int y = k8 + 8 * jm;
    const int xg = j - 9 * jm;
    const int oc0 = xg * 64;
    const int n0 = y * 64;
    const int tid = threadIdx.x;
    const int lane = tid & 63, wv = tid >> 6;
    const int wm = wv >> 1, wn = wv & 1;
    const int quad = lane >> 4, r16 = lane & 15;
    const int srow = tid >> 2, sseg = tid & 3;

    facc4 acc[2][2] = {};
    const size_t gA = (size_t)(oc0 + srow) * KG + sseg * 8;
    const size_t gB = (size_t)(n0 + srow) * KG + sseg * 8;

    uint4 vAh = *reinterpret_cast<const uint4*>(Ah + gA);
    uint4 vAl = *reinterpret_cast<const uint4*>(Al + gA);
    uint4 vBh = *reinterpret_cast<const uint4*>(Bh + gB);
    uint4 vBl = *reinterpret_cast<const uint4*>(Bl + gB);

    for (int ks = 0; ks < KG / 32; ++ks) {
        __syncthreads();
        *reinterpret_cast<uint4*>(&sAh[srow][sseg * 8]) = vAh;
        *reinterpret_cast<uint4*>(&sAl[srow][sseg * 8]) = vAl;
        *reinterpret_cast<uint4*>(&sBh[srow][sseg * 8]) = vBh;
        *reinterpret_cast<uint4*>(&sBl[srow][sseg * 8]) = vBl;
        __syncthreads();
        if (ks + 1 < KG / 32) {
            const int k0n = (ks + 1) * 32;
            vAh = *reinterpret_cast<const uint4*>(Ah + gA + k0n);
            vAl = *reinterpret_cast<const uint4*>(Al + gA + k0n);
            vBh = *reinterpret_cast<const uint4*>(Bh + gB + k0n);
            vBl = *reinterpret_cast<const uint4*>(Bl + gB + k0n);
        }
        bfrag8 ah[2], al[2], bh[2], bl[2];
#pragma unroll
        for (int i = 0; i < 2; ++i) {
            ah[i] = *reinterpret_cast<const bfrag8*>(&sAh[wm * 32 + i * 16 + r16][quad * 8]);
            al[i] = *reinterpret_cast<const bfrag8*>(&sAl[wm * 32 + i * 16 + r16][quad * 8]);
            bh[i] = *reinterpret_cast<const bfrag8*>(&sBh[wn * 32 + i * 16 + r16][quad * 8]);
            bl[i] = *reinterpret_cast<const bfrag8*>(&sBl[wn * 32 + i * 16 + r16][quad * 8]);
        }
#pragma unroll
        for (int i = 0; i < 2; ++i)
#pragma unroll
            for (int jj = 0; jj < 2; ++jj) {
                acc[i][jj] = __builtin_amdgcn_mfma_f32_16x16x32_bf16(ah[i], bh[jj], acc[i][jj], 0, 0, 0);
                acc[i][jj] = __builtin_amdgcn_mfma_f32_16x16x32_bf16(ah[i], bl[jj], acc[i][jj], 0, 0, 0);
                acc[i][jj] = __builtin_amdgcn_mfma_f32_16x16x32_bf16(al[i], bh[jj], acc[i][jj], 0, 0, 0);
            }
    }
#pragma unroll
    for (int i = 0; i < 2; ++i) {
        int oc_base = oc0 + wm * 32 + i * 16 + quad * 4;
        if (oc_base >= CH2) continue;
#pragma unroll
        for (int jj = 0; jj < 2; ++jj) {
            int n = n0 + wn * 32 + jj * 16 + r16;
            *reinterpret_cast<facc4*>(pcT + (size_t)n * CH2 + oc_base) = acc[i][jj];
        }
    }
    if (xg < 8) {
        float ps[2], pq[2];
#pragma unroll
        for (int i = 0; i < 2; ++i) {
            float sv = 0.f, qv = 0.f;
#pragma unroll
            for (int jj = 0; jj < 2; ++jj)
#pragma unroll
                for (int comp = 0; comp < 4; ++comp) {
                    float v = acc[i][jj][comp];
                    sv += v; qv = fmaf(v, v, qv);
                }
#pragma unroll
            for (int o = 32; o > 0; o >>= 1) { sv += __shfl_down(sv, o); qv += __shfl_down(qv, o); }
            ps[i] = sv; pq[i] = qv;
        }
        if (lane == 0) {
#pragma unroll
            for (int i = 0; i < 2; ++i) { sRed[wv * 4 + i * 2 + 0] = ps[i]; sRed[wv * 4 + i * 2 + 1] = pq[i]; }
        }
        __syncthreads();
        if (tid < 8) {
            int wm_ = tid >> 2, i_ = (tid >> 1) & 1, sel = tid & 1;
            float v = sRed[(2 * wm_) * 4 + i_ * 2 + sel] + sRed[(2 * wm_ + 1) * 4 + i_ * 2 + sel];
            int g = xg * 4 + wm_ * 2 + i_;
            part2[sel * 2304 + g * 72 + y] = v;
        }
    } else {
        if (wm == 0) {
#pragma unroll
            for (int i = 0; i < 2; ++i)
#pragma unroll
                for (int comp = 0; comp < 4; ++comp) {
                    float v0 = acc[i][0][comp], v1 = acc[i][1][comp];
                    float sv = v0 + v1;
                    float qv = fmaf(v0, v0, v1 * v1);
#pragma unroll
                    for (int o = 8; o > 0; o >>= 1) {
                        sv += __shfl_down(sv, o, 16);
                        qv += __shfl_down(qv, o, 16);
                    }
                    if (r16 == 0) {
                        int idx = ((wv * 4 + quad) * 2 + i) * 4 + comp;
                        sRed[idx] = sv;
                        sRed[64 + idx] = qv;
                    }
                }
        }
        __syncthreads();
        if (tid < 64) {
            int ch = tid >> 1, sel = tid & 1;
            int i_ = ch >> 4, rem = ch & 15, quad_ = rem >> 2, comp_ = rem & 3;
            int base = sel * 64;
            float v = sRed[base + ((0 * 4 + quad_) * 2 + i_) * 4 + comp_] +
                      sRed[base + ((1 * 4 + quad_) * 2 + i_) * 4 + comp_];
            part2[4608 + sel * 2304 + ch * 72 + y] = v;
        }
    }
}

// ---------------- bn2 reduce: one tiny launch, unrolled (72 partials/channel) --------
__global__ void k_bnred2(const float* __restrict__ part2,
                         const float* __restrict__ bna_g, const float* __restrict__ bna_b,
                         const float* __restrict__ bnp_g, const float* __restrict__ bnp_b,
                         float* __restrict__ bn2) {
    int t = threadIdx.x;   // 64
    if (t < 32) {
        float s = 0.f, s2 = 0.f;
#pragma unroll
        for (int yy = 0; yy < 72; ++yy) { s += part2[t * 72 + yy]; s2 += part2[2304 + t * 72 + yy]; }
        const float n = (float)(NB * DD * 36);
        float mu = s / n, var = s2 / n - mu * mu;
        float sc = bnp_g[t] * rsqrtf(var + 1e-5f);
        bn2[t] = sc; bn2[32 + t] = bnp_b[t] - mu * sc;
    } else {
        int ch = t - 32;
        float s = 0.f, s2 = 0.f;
#pragma unroll
        for (int yy = 0; yy < 72; ++yy) { s += part2[4608 + ch * 72 + yy]; s2 += part2[6912 + ch * 72 + yy]; }
        const float n = (float)(NB * 36);
        float mu = s / n, var = s2 / n - mu * mu;
        float sc = bna_g[ch] * rsqrtf(var + 1e-5f);
        bn2[64 + ch] = sc; bn2[96 + ch] = bna_b[ch] - mu * sc;
    }
}

// ---------------- digamma (args always >= 1.0 here) ----------------
__device__ __forceinline__ float digammaf_(float x) {
    float r = 0.f;
    while (x < 6.f) { r -= 1.f / x; x += 1.f; }
    float xi = 1.f / x;
    float xi2 = xi * xi;
    return r + logf(x) - 0.5f * xi -
           xi2 * (0.0833333333f - xi2 * (0.0083333333f - xi2 * 0.0039682540f));
}

// ---------------- merged routing: expectations + update + stats, prefetched -----------
// grid 256: block = (b = blk>>1, half = blk&1). 640 threads = 10 waves; wave c owns
// class c. bn2 read from global (tiny). W double-buffered in regs; P/a staged via
// register prefetch issued during the previous iteration's compute.
template <int FIRST>
__global__ __launch_bounds__(640) void k_routed(
    const float* __restrict__ pcT, const float* __restrict__ bn2g,
    const float* __restrict__ Wij,
    const float* __restrict__ S0i, const float* __restrict__ S1i, const float* __restrict__ S2i,
    float* __restrict__ S0o, float* __restrict__ S1o, float* __restrict__ S2o) {
    const int b = blockIdx.x >> 1, half = blockIdx.x & 1;
    const int tid = threadIdx.x;
    const int c = tid >> 6, lane = tid & 63;
    __shared__ float sLnp[CC][66];
    __shared__ float sBn2[128];
    __shared__ __align__(16) float sP[64][20];
    __shared__ float sA[64];
    __shared__ float sM[CC][16], sGq[CC][16], sBase[CC];
    if (tid < 128) sBn2[tid] = bn2g[tid];
    if (!FIRST && tid < 160) {
        int cc = tid >> 4, d = tid & 15;
        int bc = b * CC + cc;
        float njraw = S0i[bc] + S0i[NB * CC + bc];
        float nj = njraw + 1e-8f;
        float kappa = 1.f + nj;
        float nu = 17.f + nj;
        float s1 = S1i[bc * 16 + d] + S1i[(NB * CC + bc) * 16 + d];
        float s2v = S2i[bc * 16 + d] + S2i[(NB * CC + bc) * 16 + d];
        float xbar = s1 / nj;
        float sig = (s2v - 2.f * xbar * s1 + xbar * xbar * njraw) / nj;
        float Psi = 1.f + nj * sig + (nj / kappa) * xbar * xbar;
        sM[cc][d] = nj * xbar / kappa;
        sGq[cc][d] = 0.5f * nu / Psi;
        float term = digammaf_(0.5f * (nu + 1.f - (float)(d + 1))) - logf(Psi);
#pragma unroll
        for (int o = 8; o > 0; o >>= 1) term += __shfl_down(term, o, 16);
        if (d == 0) {
            float asum = 0.f;
#pragma unroll
            for (int k = 0; k < CC; ++k)
                asum += 1.f + S0i[b * CC + k] + S0i[NB * CC + b * CC + k] + 1e-8f;
            float elnlam = 16.f * 0.69314718056f + term;
            float elnpi = digammaf_(1.f + nj) - digammaf_(asum);
            float lb = elnpi + 0.5f * elnlam;
            sBase[cc] = lb - 8.f * 1.83787706641f - 8.f / kappa;
        }
    }
    float mc[16], Gc[16], basec = 0.f;
    float s0 = 0.f, s1[16], s2[16];
#pragma unroll
    for (int d = 0; d < 16; ++d) { s1[d] = 0.f; s2[d] = 0.f; }

    const int nbase = half * 576;
    // ---- prefetch iteration 0: W fragment + stage values ----
    alignas(16) float Wc[16], Wn[16];
    {
        int n = nbase + lane;
        int i = n / 36, xy = n - i * 36;
        const float4* wp = reinterpret_cast<const float4*>(Wij + (((size_t)i * CC + c) * 36 + xy) * 16);
        *reinterpret_cast<float4*>(&Wc[0])  = wp[0];
        *reinterpret_cast<float4*>(&Wc[4])  = wp[1];
        *reinterpret_cast<float4*>(&Wc[8])  = wp[2];
        *reinterpret_cast<float4*>(&Wc[12]) = wp[3];
    }
    const int sr = tid >> 2, sq = tid & 3;   // staging coords for tid<256
    float4 pv = {0.f, 0.f, 0.f, 0.f};
    float araw = 0.f;
    if (tid < 256) {
        int n = nbase + sr;
        int i = n / 36, xy = n - i * 36;
        pv = *reinterpret_cast<const float4*>(pcT + (size_t)(b * 36 + xy) * CH2 + i * 16 + sq * 4);
    } else if (tid < 320) {
        int n = nbase + (tid - 256);
        int i = n / 36, xy = n - i * 36;
        araw = pcT[(size_t)(b * 36 + xy) * CH2 + BB * DD + i];
    }
    __syncthreads();   // sBn2 / sM ready (also covers prologue)

#pragma unroll 1
    for (int it = 0; it < 9; ++it) {
        // write staged values to LDS (prev readers done at sync B of it-1 / prologue sync)
        if (tid < 256) {
            int n = nbase + it * 64 + sr;
            int i = n / 36;
            float psc = sBn2[i], psh = sBn2[32 + i];
            float4 v = pv;
            v.x = fmaf(v.x, psc, psh); v.y = fmaf(v.y, psc, psh);
            v.z = fmaf(v.z, psc, psh); v.w = fmaf(v.w, psc, psh);
            *reinterpret_cast<float4*>(&sP[sr][sq * 4]) = v;
        } else if (tid < 320) {
            int n = nbase + it * 64 + (tid - 256);
            int i = n / 36;
            float va = fmaf(araw, sBn2[64 + i], sBn2[96 + i]);
            sA[tid - 256] = 1.f / (1.f + expf(-va));
        }
        if (!FIRST && it == 0) {
#pragma unroll
            for (int d = 0; d < 16; ++d) { mc[d] = sM[c][d]; Gc[d] = sGq[c][d]; }
            basec = sBase[c];
        }
        __syncthreads();   // A: sP/sA ready
        alignas(16) float P[16];
        *reinterpret_cast<float4*>(&P[0])  = *reinterpret_cast<const float4*>(&sP[lane][0]);
        *reinterpret_cast<float4*>(&P[4])  = *reinterpret_cast<const float4*>(&sP[lane][4]);
        *reinterpret_cast<float4*>(&P[8])  = *reinterpret_cast<const float4*>(&sP[lane][8]);
        *reinterpret_cast<float4*>(&P[12]) = *reinterpret_cast<const float4*>(&sP[lane][12]);
        float V[16];
#pragma unroll
        for (int p = 0; p < 4; ++p)
#pragma unroll
            for (int r = 0; r < 4; ++r)
                V[p * 4 + r] = Wc[p * 4 + 0] * P[0 + r] + Wc[p * 4 + 1] * P[4 + r] +
                               Wc[p * 4 + 2] * P[8 + r] + Wc[p * 4 + 3] * P[12 + r];
        float av = sA[lane];
        // ---- prefetch iteration it+1 (lands during softmax + barriers) ----
        if (it < 8) {
            int nx = nbase + (it + 1) * 64 + lane;
            int ix = nx / 36, xyx = nx - ix * 36;
            const float4* wp = reinterpret_cast<const float4*>(Wij + (((size_t)ix * CC + c) * 36 + xyx) * 16);
            *reinterpret_cast<float4*>(&Wn[0])  = wp[0];
            *reinterpret_cast<float4*>(&Wn[4])  = wp[1];
            *reinterpret_cast<float4*>(&Wn[8])  = wp[2];
            *reinterpret_cast<float4*>(&Wn[12]) = wp[3];
            if (tid < 256) {
                int n = nbase + (it + 1) * 64 + sr;
                int i = n / 36, xy = n - i * 36;
                pv = *reinterpret_cast<const float4*>(pcT + (size_t)(b * 36 + xy) * CH2 + i * 16 + sq * 4);
            } else if (tid < 320) {
                int n = nbase + (it + 1) * 64 + (tid - 256);
                int i = n / 36, xy = n - i * 36;
                araw = pcT[(size_t)(b * 36 + xy) * CH2 + BB * DD + i];
            }
        }
        float wgt;
        if (FIRST) {
            wgt = 0.1f * av;
            __syncthreads();   // B: all reads of sP/sA done before next stage
        } else {
            float q = 0.f;
#pragma unroll
            for (int d = 0; d < 16; ++d) {
                float dm = V[d] - mc[d];
                q = fmaf(dm * dm, Gc[d], q);
            }
            float lnp = basec - q;
            sLnp[c][lane] = lnp;
            __syncthreads();   // B: sLnp ready; sP/sA reads done
            float mx = -1e30f;
#pragma unroll
            for (int cc = 0; cc < CC; ++cc) mx = fmaxf(mx, sLnp[cc][lane]);
            float ssum = 0.f;
#pragma unroll
            for (int cc = 0; cc < CC; ++cc) ssum += expf(sLnp[cc][lane] - mx);
            wgt = expf(lnp - mx) / ssum * av;
        }
        s0 += wgt;
#pragma unroll
        for (int d = 0; d < 16; ++d) {
            float wv = wgt * V[d];
            s1[d] += wv;
            s2[d] = fmaf(wv, V[d], s2[d]);
        }
        if (it < 8) {
#pragma unroll
            for (int d = 0; d < 16; ++d) Wc[d] = Wn[d];
        }
    }
#pragma unroll
    for (int o = 32; o > 0; o >>= 1) {
        s0 += __shfl_down(s0, o);
#pragma unroll
        for (int k = 0; k < 16; ++k) {
            s1[k] += __shfl_down(s1[k], o);
            s2[k] += __shfl_down(s2[k], o);
        }
    }
    if (lane == 0) {
        int idx = half * (NB * CC) + b * CC + c;
        S0o[idx] = s0;
#pragma unroll
        for (int k = 0; k < 16; ++k) { S1o[idx * 16 + k] = s1[k]; S2o[idx * 16 + k] = s2[k]; }
    }
}

// ---------------- final: expectations (logits) inline + BN over batch + sigmoid -------
__global__ void k_final2(const float* __restrict__ S0p, const float* __restrict__ S1p,
                         const float* __restrict__ S2p, float* __restrict__ out) {
    int c = blockIdx.x;      // 10 blocks
    int b = threadIdx.x;     // 128 threads
    int bc = b * CC + c;
    float njraw = S0p[bc] + S0p[NB * CC + bc];
    float nj = njraw + 1e-8f;
    float asum = 0.f;
#pragma unroll
    for (int k = 0; k < CC; ++k)
        asum += 1.f + S0p[b * CC + k] + S0p[NB * CC + b * CC + k] + 1e-8f;
    float kappa = 1.f + nj;
    float nu = 17.f + nj;
    float elnlam = 16.f * 0.69314718056f;
    for (int d = 0; d < 16; ++d) {
        float s1 = S1p[bc * 16 + d] + S1p[(NB * CC + bc) * 16 + d];
        float s2v = S2p[bc * 16 + d] + S2p[(NB * CC + bc) * 16 + d];
        float xbar = s1 / nj;
        float sig = (s2v - 2.f * xbar * s1 + xbar * xbar * njraw) / nj;
        float Psi = 1.f + nj * sig + (nj / kappa) * xbar * xbar;
        elnlam += digammaf_(0.5f * (nu + 1.f - (float)(d + 1))) - logf(Psi);
    }
    float elnpi = digammaf_(1.f + nj) - digammaf_(asum);
    float v = elnpi + 0.5f * elnlam;
    float s = v, s2 = v * v;
#pragma unroll
    for (int o = 32; o > 0; o >>= 1) { s += __shfl_down(s, o); s2 += __shfl_down(s2, o); }
    __shared__ float ls[2], lq[2];
    int lane = b & 63, wid = b >> 6;
    if (lane == 0) { ls[wid] = s; lq[wid] = s2; }
    __syncthreads();
    float mu = (ls[0] + ls[1]) * (1.f / 128.f);
    float var = (lq[0] + lq[1]) * (1.f / 128.f) - mu * mu;
    out[b * CC + c] = 1.f / (1.f + expf(-(v - mu) * rsqrtf(var + 1e-5f)));
}

extern "C" void kernel_launch(void* const* d_in, const int* in_sizes, int n_in,
                              void* d_out, int out_size, void* d_ws, size_t ws_size,
                              hipStream_t stream) {
    (void)in_sizes; (void)n_in; (void)out_size; (void)ws_size;
    const float* x       = (const float*)d_in[0];
    const float* conv1_w = (const float*)d_in[1];
    const float* bn1_g   = (const float*)d_in[2];
    const float* bn1_b   = (const float*)d_in[3];
    const float* prim_w  = (const float*)d_in[4];
    const float* bna_g   = (const float*)d_in[5];
    const float* bna_b   = (const float*)d_in[6];
    const float* bnp_g   = (const float*)d_in[7];
    const float* bnp_b   = (const float*)d_in[8];
    const float* Wij     = (const float*)d_in[9];

    float* ws = (float*)d_ws;
    float* h   = ws;                                          // 3,211,264 f32
    float* pcT = ws + 3211264;                                // 2,506,752 f32 [4608][544]
    unsigned short* Bh = (unsigned short*)(ws + 5718016);     // 5,308,416 bf16
    unsigned short* Bl = (unsigned short*)(ws + 8372224);     // 5,308,416 bf16
    unsigned short* Ahp = (unsigned short*)(ws + 11026432);   //   663,552 bf16
    unsigned short* Alp = (unsigned short*)(ws + 11358208);   //   663,552 bf16
    float* bn1    = ws + 11689984;   // 256
    float* bn2    = ws + 11690240;   // 128
    float* S0a    = ws + 11690368;   // 2,560
    float* S1a    = ws + 11692928;   // 40,960
    float* S2a    = ws + 11733888;   // 40,960
    float* S0b    = ws + 11774848;   // 2,560
    float* S1b    = ws + 11777408;   // 40,960
    float* S2b    = ws + 11818368;   // 40,960
    float* part1s = ws + 11859328;   // 16,384
    float* part1q = ws + 11875712;   // 16,384
    float* part2  = ws + 11892096;   // 9,216
    float* out    = (float*)d_out;

    k_conv1<<<dim3(8, 128), 256, 0, stream>>>(x, conv1_w, h, part1s, part1q);
    k_bnred1<<<128, 256, 0, stream>>>(part1s, part1q, bn1_g, bn1_b, bn1);
    k_pim<<<2916, 256, 0, stream>>>(prim_w, h, bn1, Ahp, Alp, Bh, Bl);
    k_gemm<<<648, 256, 0, stream>>>(Ahp, Alp, Bh, Bl, pcT, part2);
    k_bnred2<<<1, 64, 0, stream>>>(part2, bna_g, bna_b, bnp_g, bnp_b, bn2);

    // routing: iter0 (R = 1/C) -> A; iter1 (expect from A) -> B; iter2 (expect from B) -> A
    k_routed<1><<<256, 640, 0, stream>>>(pcT, bn2, Wij, S0a, S1a, S2a, S0a, S1a, S2a);
    k_routed<0><<<256, 640, 0, stream>>>(pcT, bn2, Wij, S0a, S1a, S2a, S0b, S1b, S2b);
    k_routed<0><<<256, 640, 0, stream>>>(pcT, bn2, Wij, S0b, S1b, S2b, S0a, S1a, S2a);
    k_final2<<<10, 128, 0, stream>>>(S0a, S1a, S2a, out);
}